// Round 1
// baseline (462.913 us; speedup 1.0000x reference)
//
#include <hip/hip_runtime.h>
#include <math.h>

#define BB 32
#define FF 512
#define TT 4000
#define HH 8
#define DKK 64
#define DVV 64
#define NT4 1000  // TT/4

// ---------------------------------------------------------------------------
// prep_qk: qk[h*512+f] = (1/8) * sum_d q[h,d] * Wk[h*64+d, f]
//          qb[h]       = (1/8) * sum_d q[h,d] * bk[h*64+d]
// grid 16 x 256 (4096 threads, one per (h,f))
// ---------------------------------------------------------------------------
__global__ __launch_bounds__(256) void prep_qk(const float* __restrict__ q,
                                               const float* __restrict__ Wk,
                                               const float* __restrict__ bk,
                                               float* __restrict__ qk,
                                               float* __restrict__ qb) {
    int gid = blockIdx.x * 256 + threadIdx.x;   // 0..4095
    int h = gid >> 9, f = gid & 511;
    float s = 0.f;
#pragma unroll 8
    for (int d = 0; d < DKK; ++d)
        s += q[h * DKK + d] * Wk[(size_t)(h * DKK + d) * FF + f];
    qk[gid] = s * 0.125f;
    if (gid < HH) {
        float sb = 0.f;
        for (int d = 0; d < DKK; ++d) sb += q[gid * DKK + d] * bk[gid * DKK + d];
        qb[gid] = sb * 0.125f;
    }
}

// ---------------------------------------------------------------------------
// prep_wvt: WvT[f*512 + hv] = Wv[hv*512 + f]   (1 MB transpose, done once)
// grid 1024 x 256
// ---------------------------------------------------------------------------
__global__ __launch_bounds__(256) void prep_wvt(const float* __restrict__ Wv,
                                                float* __restrict__ WvT) {
    int gid = blockIdx.x * 256 + threadIdx.x;   // 0..262143
    int hv = gid >> 9, f = gid & 511;
    WvT[f * 512 + hv] = Wv[gid];
}

// ---------------------------------------------------------------------------
// k_scores: sc[b,h,t] = qb[h] + sum_f qk[h,f] * x[b,f,t]
// grid (16, 32) = (t-tile of 256, b); 256 threads = 4 waves.
// wave w handles f in [w*128, w*128+128); lane l handles t = t0 + 4*l (float4)
// partials reduced across waves through LDS.
// ---------------------------------------------------------------------------
__global__ __launch_bounds__(256) void k_scores(const float* __restrict__ x,
                                                const float* __restrict__ qk,
                                                const float* __restrict__ qb,
                                                float* __restrict__ sc) {
    __shared__ float4 part[HH * 4 * 64];  // [h][w][l], 32 KB
    int b = blockIdx.y, tt = blockIdx.x;
    int tid = threadIdx.x, w = tid >> 6, l = tid & 63;
    int t0 = tt << 8;
    int t = t0 + (l << 2);
    float4 acc[HH];
#pragma unroll
    for (int h = 0; h < HH; ++h) acc[h] = make_float4(0.f, 0.f, 0.f, 0.f);
    if (t < TT) {
        const float* xp = x + (size_t)b * FF * TT + t;
        int f40 = w * 32;
        for (int f4 = f40; f4 < f40 + 32; ++f4) {
            int f = f4 << 2;
            float4 xv0 = *(const float4*)(xp + (size_t)(f + 0) * TT);
            float4 xv1 = *(const float4*)(xp + (size_t)(f + 1) * TT);
            float4 xv2 = *(const float4*)(xp + (size_t)(f + 2) * TT);
            float4 xv3 = *(const float4*)(xp + (size_t)(f + 3) * TT);
#pragma unroll
            for (int h = 0; h < HH; ++h) {
                float4 qv = *(const float4*)(qk + h * FF + f);
                acc[h].x += qv.x * xv0.x + qv.y * xv1.x + qv.z * xv2.x + qv.w * xv3.x;
                acc[h].y += qv.x * xv0.y + qv.y * xv1.y + qv.z * xv2.y + qv.w * xv3.y;
                acc[h].z += qv.x * xv0.z + qv.y * xv1.z + qv.z * xv2.z + qv.w * xv3.z;
                acc[h].w += qv.x * xv0.w + qv.y * xv1.w + qv.z * xv2.w + qv.w * xv3.w;
            }
        }
    }
#pragma unroll
    for (int h = 0; h < HH; ++h) part[(h * 4 + w) * 64 + l] = acc[h];
    __syncthreads();
    for (int p = tid; p < 512; p += 256) {
        int h = p >> 6, ll = p & 63;
        int t2 = t0 + (ll << 2);
        if (t2 >= TT) continue;
        float4 a0 = part[(h * 4 + 0) * 64 + ll];
        float4 a1 = part[(h * 4 + 1) * 64 + ll];
        float4 a2 = part[(h * 4 + 2) * 64 + ll];
        float4 a3 = part[(h * 4 + 3) * 64 + ll];
        float qbh = qb[h];
        float4 o;
        o.x = a0.x + a1.x + a2.x + a3.x + qbh;
        o.y = a0.y + a1.y + a2.y + a3.y + qbh;
        o.z = a0.z + a1.z + a2.z + a3.z + qbh;
        o.w = a0.w + a1.w + a2.w + a3.w + qbh;
        *(float4*)(sc + ((size_t)(b * HH + h)) * TT + t2) = o;
    }
}

// ---------------------------------------------------------------------------
// k_softmax: per (b,h) row of 4000: apply mask (weights==0 -> -1e30),
// softmax in place. Masked entries end exactly 0 (exp underflow).
// grid 256 blocks (b*8+h), 256 threads.
// ---------------------------------------------------------------------------
__global__ __launch_bounds__(256) void k_softmax(float* __restrict__ sc,
                                                 const int* __restrict__ wts) {
    __shared__ float s4[4];
    int bh = blockIdx.x, b = bh >> 3;
    int tid = threadIdx.x, w = tid >> 6, l = tid & 63;
    float* row = sc + (size_t)bh * TT;
    const int* wr = wts + (size_t)b * TT;
    float4 v[4];
    float m = -3.0e38f;
#pragma unroll
    for (int k = 0; k < 4; ++k) {
        int i = tid + k * 256;
        if (i < NT4) {
            float4 s = *(const float4*)(row + (i << 2));
            int4 wv = *(const int4*)(wr + (i << 2));
            if (wv.x == 0) s.x = -1e30f;
            if (wv.y == 0) s.y = -1e30f;
            if (wv.z == 0) s.z = -1e30f;
            if (wv.w == 0) s.w = -1e30f;
            v[k] = s;
            m = fmaxf(m, fmaxf(fmaxf(s.x, s.y), fmaxf(s.z, s.w)));
        }
    }
#pragma unroll
    for (int d = 1; d < 64; d <<= 1) m = fmaxf(m, __shfl_xor(m, d));
    if (l == 0) s4[w] = m;
    __syncthreads();
    m = fmaxf(fmaxf(s4[0], s4[1]), fmaxf(s4[2], s4[3]));
    __syncthreads();
    float lsum = 0.f;
#pragma unroll
    for (int k = 0; k < 4; ++k) {
        int i = tid + k * 256;
        if (i < NT4) {
            float4 s = v[k];
            s.x = __expf(s.x - m);
            s.y = __expf(s.y - m);
            s.z = __expf(s.z - m);
            s.w = __expf(s.w - m);
            v[k] = s;
            lsum += s.x + s.y + s.z + s.w;
        }
    }
#pragma unroll
    for (int d = 1; d < 64; d <<= 1) lsum += __shfl_xor(lsum, d);
    if (l == 0) s4[w] = lsum;
    __syncthreads();
    lsum = s4[0] + s4[1] + s4[2] + s4[3];
    // all-masked row guard: m stays at -1e30 -> output zeros (matches ref)
    float inv = (m <= -1e29f) ? 0.f : (1.f / lsum);
#pragma unroll
    for (int k = 0; k < 4; ++k) {
        int i = tid + k * 256;
        if (i < NT4) {
            float4 s = v[k];
            s.x *= inv; s.y *= inv; s.z *= inv; s.w *= inv;
            *(float4*)(row + (i << 2)) = s;
        }
    }
}

// ---------------------------------------------------------------------------
// k_y: y[b,h,f] = sum_t attn[b,h,t] * x[b,f,t]
// grid (128, 32) = (f-chunk of 4, b); 256 threads stride over t in float4s.
// Per thread: 32 scalar accumulators (8 h x 4 f). Cross-thread reduction via
// padded LDS (stride 257 -> conflict-free).
// ---------------------------------------------------------------------------
__global__ __launch_bounds__(256) void k_y(const float* __restrict__ x,
                                           const float* __restrict__ attn,
                                           float* __restrict__ y) {
    __shared__ float red[32 * 257];  // ~32.1 KB
    int b = blockIdx.y, ft = blockIdx.x;
    int tid = threadIdx.x;
    int f0 = ft << 2;
    float acc[8][4];
#pragma unroll
    for (int h = 0; h < 8; ++h)
#pragma unroll
        for (int f = 0; f < 4; ++f) acc[h][f] = 0.f;
    const float* ab = attn + (size_t)b * HH * TT;
    const float* xb = x + ((size_t)b * FF + f0) * TT;
    for (int i = tid; i < NT4; i += 256) {
        int t = i << 2;
        float4 a[8];
#pragma unroll
        for (int h = 0; h < 8; ++h) a[h] = *(const float4*)(ab + (size_t)h * TT + t);
        float4 xv[4];
#pragma unroll
        for (int f = 0; f < 4; ++f) xv[f] = *(const float4*)(xb + (size_t)f * TT + t);
#pragma unroll
        for (int h = 0; h < 8; ++h)
#pragma unroll
            for (int f = 0; f < 4; ++f)
                acc[h][f] += a[h].x * xv[f].x + a[h].y * xv[f].y +
                             a[h].z * xv[f].z + a[h].w * xv[f].w;
    }
#pragma unroll
    for (int o = 0; o < 32; ++o) red[o * 257 + tid] = acc[o >> 2][o & 3];
    __syncthreads();
    if (tid < 32) {
        float vsum = 0.f;
        for (int j = 0; j < 256; ++j) vsum += red[tid * 257 + j];
        int h = tid >> 2, fo = tid & 3;
        y[((size_t)b * HH + h) * FF + f0 + fo] = vsum;
    }
}

// ---------------------------------------------------------------------------
// k_out: out[b, h*64+v] = bv[h*64+v] + sum_f WvT[f,h*64+v] * y[b,h,f]
// grid (8, 32) = (h, b); 64 threads (v). y-row staged in LDS.
// ---------------------------------------------------------------------------
__global__ __launch_bounds__(64) void k_out(const float* __restrict__ y,
                                            const float* __restrict__ WvT,
                                            const float* __restrict__ bv,
                                            float* __restrict__ out) {
    __shared__ float ys[FF];
    int h = blockIdx.x, b = blockIdx.y, tid = threadIdx.x;
    const float* yr = y + ((size_t)b * HH + h) * FF;
    for (int i = tid; i < FF; i += 64) ys[i] = yr[i];
    __syncthreads();
    float acc = 0.f;
    int hv = (h << 6) + tid;
    for (int f = 0; f < FF; ++f)
        acc += ys[f] * WvT[f * 512 + hv];
    out[b * 512 + hv] = acc + bv[hv];
}

// ---------------------------------------------------------------------------
// Workspace layout (floats):
//   qk     at       0  (4096)
//   qb     at    4096  (8)
//   WvT    at    8192  (262144)
//   scores at  270336  (1024000)   -- becomes attn in place
//   y      at 1294336  (131072)
// total 1425408 floats = 5.7 MB
// ---------------------------------------------------------------------------
extern "C" void kernel_launch(void* const* d_in, const int* in_sizes, int n_in,
                              void* d_out, int out_size, void* d_ws, size_t ws_size,
                              hipStream_t stream) {
    const float* x  = (const float*)d_in[0];
    const int*   wts = (const int*)d_in[1];
    const float* q  = (const float*)d_in[2];
    const float* Wk = (const float*)d_in[3];
    const float* bk = (const float*)d_in[4];
    const float* Wv = (const float*)d_in[5];
    const float* bv = (const float*)d_in[6];
    float* out = (float*)d_out;
    float* ws = (float*)d_ws;

    float* qk  = ws;
    float* qb  = ws + 4096;
    float* WvT = ws + 8192;
    float* sc  = ws + 270336;
    float* y   = ws + 1294336;

    prep_qk<<<16, 256, 0, stream>>>(q, Wk, bk, qk, qb);
    prep_wvt<<<1024, 256, 0, stream>>>(Wv, WvT);
    k_scores<<<dim3(16, 32), 256, 0, stream>>>(x, qk, qb, sc);
    k_softmax<<<256, 256, 0, stream>>>(sc, wts);
    k_y<<<dim3(128, 32), 256, 0, stream>>>(x, sc, y);
    k_out<<<dim3(8, 32), 64, 0, stream>>>(y, WvT, bv, out);
}